// Round 2
// baseline (650.758 us; speedup 1.0000x reference)
//
#include <hip/hip_runtime.h>
#include <hip/hip_bf16.h>

typedef float f32x4 __attribute__((ext_vector_type(4)));
typedef __bf16 bf16x8 __attribute__((ext_vector_type(8)));
typedef unsigned short ushort_t;
typedef ushort_t u16x8 __attribute__((ext_vector_type(8)));

#define GLDS16(gp, lp)                                                        \
  __builtin_amdgcn_global_load_lds(                                           \
      (__attribute__((address_space(1))) void*)(gp),                          \
      (__attribute__((address_space(3))) void*)(lp), 16, 0, 0)

__device__ __forceinline__ ushort_t f2bf(float f) {
  unsigned u = __float_as_uint(f);
  unsigned r = u + 0x7fffu + ((u >> 16) & 1u);  // round-to-nearest-even
  return (ushort_t)(r >> 16);
}

// LDS k-chunk swizzle: kills the 8-way ds_read_b128 bank conflicts while
// keeping the GLDS "dest = base + lane*16" contiguity (we permute which
// GLOBAL chunk a lane fetches, not where it lands in LDS).
__device__ __forceinline__ int swz(int row) {
  return (row & 3) ^ ((row >> 2) & 3);
}

// ---------------------------------------------------------------------------
// Kernel: W1 [K=1024][N=1024] fp32 -> w1t [N][K] bf16 (transpose + convert)
// ---------------------------------------------------------------------------
__global__ __launch_bounds__(256) void prep_w1(const float* __restrict__ w1,
                                               ushort_t* __restrict__ w1t) {
  __shared__ ushort_t tile[64][80];
  const int k0 = blockIdx.x * 64;
  const int n0 = blockIdx.y * 64;
  const int tid = threadIdx.x;
#pragma unroll
  for (int it = 0; it < 16; ++it) {
    int idx = it * 256 + tid;
    int k = idx >> 6, n = idx & 63;
    tile[n][k] = f2bf(w1[(size_t)(k0 + k) * 1024 + n0 + n]);
  }
  __syncthreads();
#pragma unroll
  for (int it = 0; it < 2; ++it) {
    int idx = it * 256 + tid;
    int n = idx >> 3, kk = (idx & 7) * 8;
    bf16x8 v = *(const bf16x8*)&tile[n][kk];
    *(bf16x8*)&w1t[(size_t)(n0 + n) * 1024 + k0 + kk] = v;
  }
}

// ---------------------------------------------------------------------------
// Kernel: x fp32 [64M] -> xbf bf16 (row-major [65536][1024])
// ---------------------------------------------------------------------------
__global__ __launch_bounds__(256) void prep_x(const float* __restrict__ x,
                                              ushort_t* __restrict__ xbf) {
  size_t i = ((size_t)blockIdx.x * 256 + threadIdx.x) * 8;
  float4 a = *(const float4*)(x + i);
  float4 b = *(const float4*)(x + i + 4);
  u16x8 o;
  o[0] = f2bf(a.x); o[1] = f2bf(a.y); o[2] = f2bf(a.z); o[3] = f2bf(a.w);
  o[4] = f2bf(b.x); o[5] = f2bf(b.y); o[6] = f2bf(b.z); o[7] = f2bf(b.w);
  *(u16x8*)(xbf + i) = o;
}

// ---------------------------------------------------------------------------
// GEMM: each block owns 128 rows of x and loops over ALL 8 n-tiles of w1t
// (x strip read once, w1t L2-resident). Per n-tile: relu + dot-w2 folded
// into per-row register accumulators. Emits final logits[65536].
// ---------------------------------------------------------------------------
template <bool A_BF16>
__global__ __launch_bounds__(256) void gemm_logits(
    const void* __restrict__ aglob, const ushort_t* __restrict__ w1t,
    const float* __restrict__ b1, const float* __restrict__ w2,
    float* __restrict__ logits) {
  __shared__ ushort_t As[128 * 32];  // 8 KB
  __shared__ ushort_t Bs[128 * 32];  // 8 KB
  const int tid = threadIdx.x;
  const int wave = tid >> 6, lane = tid & 63;
  const int quad = lane >> 4, lc = lane & 15;
  const int m0 = blockIdx.x * 128;
  const int wm = (wave & 1) * 64, wn = (wave >> 1) * 64;

  // Staging: lane idx covers LDS chunk idx*16B; fetches swizzled global chunk.
  const int g0 = tid, g1 = 256 + tid;
  const int r0 = g0 >> 2, c0 = (g0 & 3) ^ swz(g0 >> 2);
  const int r1 = g1 >> 2, c1 = (g1 & 3) ^ swz(g1 >> 2);
  ushort_t* adst0 = As + g0 * 8;
  ushort_t* adst1 = As + g1 * 8;
  ushort_t* bdst0 = Bs + g0 * 8;
  ushort_t* bdst1 = Bs + g1 * 8;
  const ushort_t* abf0 = nullptr; const ushort_t* abf1 = nullptr;
  const float* af32_0 = nullptr; const float* af32_1 = nullptr;
  if constexpr (A_BF16) {
    abf0 = (const ushort_t*)aglob + (size_t)(m0 + r0) * 1024 + c0 * 8;
    abf1 = (const ushort_t*)aglob + (size_t)(m0 + r1) * 1024 + c1 * 8;
  } else {
    af32_0 = (const float*)aglob + (size_t)(m0 + r0) * 1024 + c0 * 8;
    af32_1 = (const float*)aglob + (size_t)(m0 + r1) * 1024 + c1 * 8;
  }
  const ushort_t* bbase0 = w1t + (size_t)r0 * 1024 + c0 * 8;
  const ushort_t* bbase1 = w1t + (size_t)r1 * 1024 + c1 * 8;

  // Fragment read offsets (swizzled), fixed for the whole kernel.
  int aoff[4], boff[4];
#pragma unroll
  for (int mi = 0; mi < 4; ++mi) {
    int r = wm + mi * 16 + lc;
    aoff[mi] = r * 32 + (quad ^ swz(r)) * 8;
  }
#pragma unroll
  for (int ni = 0; ni < 4; ++ni) {
    int r = wn + ni * 16 + lc;
    boff[ni] = r * 32 + (quad ^ swz(r)) * 8;
  }

  float racc[4][4] = {};  // per-row logit partials, accumulated across n-tiles

  for (int nt = 0; nt < 8; ++nt) {
    f32x4 acc[4][4] = {};
    const ushort_t* bp0 = bbase0 + (size_t)nt * 128 * 1024;
    const ushort_t* bp1 = bbase1 + (size_t)nt * 128 * 1024;
    for (int kt = 0; kt < 32; ++kt) {
      const int k0 = kt * 32;
      __syncthreads();  // prior iteration's LDS reads done
      GLDS16(bp0 + k0, bdst0);
      GLDS16(bp1 + k0, bdst1);
      if constexpr (A_BF16) {
        GLDS16(abf0 + k0, adst0);
        GLDS16(abf1 + k0, adst1);
      } else {
        float4 v0 = *(const float4*)(af32_0 + k0);
        float4 v1 = *(const float4*)(af32_0 + k0 + 4);
        float4 v2 = *(const float4*)(af32_1 + k0);
        float4 v3 = *(const float4*)(af32_1 + k0 + 4);
        u16x8 o0, o1;
        o0[0] = f2bf(v0.x); o0[1] = f2bf(v0.y); o0[2] = f2bf(v0.z); o0[3] = f2bf(v0.w);
        o0[4] = f2bf(v1.x); o0[5] = f2bf(v1.y); o0[6] = f2bf(v1.z); o0[7] = f2bf(v1.w);
        o1[0] = f2bf(v2.x); o1[1] = f2bf(v2.y); o1[2] = f2bf(v2.z); o1[3] = f2bf(v2.w);
        o1[4] = f2bf(v3.x); o1[5] = f2bf(v3.y); o1[6] = f2bf(v3.z); o1[7] = f2bf(v3.w);
        *(u16x8*)adst0 = o0;
        *(u16x8*)adst1 = o1;
      }
      __syncthreads();  // staging visible (vmcnt drained by barrier)

      bf16x8 afr[4], bfr[4];
#pragma unroll
      for (int mi = 0; mi < 4; ++mi) afr[mi] = *(const bf16x8*)&As[aoff[mi]];
#pragma unroll
      for (int ni = 0; ni < 4; ++ni) bfr[ni] = *(const bf16x8*)&Bs[boff[ni]];
#pragma unroll
      for (int mi = 0; mi < 4; ++mi)
#pragma unroll
        for (int ni = 0; ni < 4; ++ni)
          acc[mi][ni] = __builtin_amdgcn_mfma_f32_16x16x32_bf16(
              afr[mi], bfr[ni], acc[mi][ni], 0, 0, 0);
    }
    // n-tile epilogue: relu(h+b1)*w2 folded into racc (K complete for this nt)
    float bv[4], wv[4];
#pragma unroll
    for (int ni = 0; ni < 4; ++ni) {
      int col = nt * 128 + wn + ni * 16 + lc;
      bv[ni] = b1[col];
      wv[ni] = w2[col];
    }
#pragma unroll
    for (int mi = 0; mi < 4; ++mi)
#pragma unroll
      for (int r = 0; r < 4; ++r) {
        float s = 0.f;
#pragma unroll
        for (int ni = 0; ni < 4; ++ni) {
          float h = acc[mi][ni][r] + bv[ni];
          h = h > 0.f ? h : 0.f;
          s += h * wv[ni];
        }
        racc[mi][r] += s;
      }
  }

  // Butterfly over the 16 columns held per lane-group, then cross-wave add.
#pragma unroll
  for (int mi = 0; mi < 4; ++mi)
#pragma unroll
    for (int r = 0; r < 4; ++r)
#pragma unroll
      for (int off = 1; off < 16; off <<= 1)
        racc[mi][r] += __shfl_xor(racc[mi][r], off, 64);
  __syncthreads();  // all LDS reads done; reuse As as scratch
  float* lbuf = (float*)As;
  if (tid < 128) lbuf[tid] = 0.f;
  __syncthreads();
  if (lc == 0) {
#pragma unroll
    for (int mi = 0; mi < 4; ++mi)
#pragma unroll
      for (int r = 0; r < 4; ++r)
        atomicAdd(&lbuf[wm + mi * 16 + quad * 4 + r], racc[mi][r]);
  }
  __syncthreads();
  // b2 omitted: softmax is shift-invariant.
  if (tid < 128) logits[m0 + tid] = lbuf[tid];
}

// ---------------------------------------------------------------------------
// Pooling: per 2x2 window, softmax over 4 ready-made logits, weighted sum of
// the 4 fp32 x rows.
// ---------------------------------------------------------------------------
__global__ __launch_bounds__(256) void pool_out(const float* __restrict__ x,
                                                const float* __restrict__ logits,
                                                float* __restrict__ out) {
  const int win = blockIdx.x;  // b*1024 + r
  const int b = win >> 10, r = win & 1023;
  const int i = r >> 5, j = r & 31;
  const int m = b * 4096 + i * 128 + j * 2;
  const int tid = threadIdx.x;
  float l0 = logits[m], l1 = logits[m + 1];
  float l2 = logits[m + 64], l3 = logits[m + 65];
  float mx = fmaxf(fmaxf(l0, l1), fmaxf(l2, l3));
  float e0 = __expf(l0 - mx), e1 = __expf(l1 - mx);
  float e2 = __expf(l2 - mx), e3 = __expf(l3 - mx);
  float inv = 1.0f / (e0 + e1 + e2 + e3);
  e0 *= inv; e1 *= inv; e2 *= inv; e3 *= inv;

  const size_t base = (size_t)m * 1024;
  const float4* x0 = (const float4*)(x + base);
  const float4* x1 = (const float4*)(x + base + 1024);
  const float4* x2 = (const float4*)(x + base + 64 * 1024);
  const float4* x3 = (const float4*)(x + base + 65 * 1024);
  float4 v0 = x0[tid], v1 = x1[tid], v2 = x2[tid], v3 = x3[tid];
  float4 o;
  o.x = e0 * v0.x + e1 * v1.x + e2 * v2.x + e3 * v3.x;
  o.y = e0 * v0.y + e1 * v1.y + e2 * v2.y + e3 * v3.y;
  o.z = e0 * v0.z + e1 * v1.z + e2 * v2.z + e3 * v3.z;
  o.w = e0 * v0.w + e1 * v1.w + e2 * v2.w + e3 * v3.w;
  ((float4*)out)[(size_t)win * 256 + tid] = o;
}

// ---------------------------------------------------------------------------
extern "C" void kernel_launch(void* const* d_in, const int* in_sizes, int n_in,
                              void* d_out, int out_size, void* d_ws,
                              size_t ws_size, hipStream_t stream) {
  const float* x  = (const float*)d_in[0];  // [16, 4096, 1024]
  const float* W1 = (const float*)d_in[1];  // [1024, 1024]
  const float* b1 = (const float*)d_in[2];  // [1024]
  const float* W2 = (const float*)d_in[3];  // [1024, 1]
  float* out = (float*)d_out;               // [16, 1024, 1024]

  const size_t XBF_BYTES = 134217728ull;  // 64M bf16
  const size_t W1T_BYTES = 2097152ull;
  const size_t LGT_BYTES = 262144ull;

  if (ws_size >= XBF_BYTES + W1T_BYTES + LGT_BYTES) {
    ushort_t* xbf = (ushort_t*)d_ws;
    ushort_t* w1t = (ushort_t*)((char*)d_ws + XBF_BYTES);
    float* logits = (float*)((char*)d_ws + XBF_BYTES + W1T_BYTES);
    prep_x<<<32768, 256, 0, stream>>>(x, xbf);
    prep_w1<<<dim3(16, 16), 256, 0, stream>>>(W1, w1t);
    gemm_logits<true><<<512, 256, 0, stream>>>(xbf, w1t, b1, W2, logits);
    pool_out<<<16384, 256, 0, stream>>>(x, logits, out);
  } else {
    // Fallback: convert A on the fly (no xbf scratch needed).
    ushort_t* w1t = (ushort_t*)d_ws;
    float* logits = (float*)((char*)d_ws + W1T_BYTES);
    prep_w1<<<dim3(16, 16), 256, 0, stream>>>(W1, w1t);
    gemm_logits<false><<<512, 256, 0, stream>>>(x, w1t, b1, W2, logits);
    pool_out<<<16384, 256, 0, stream>>>(x, logits, out);
  }
}

// Round 3
// 582.175 us; speedup vs baseline: 1.1178x; 1.1178x over previous
//
#include <hip/hip_runtime.h>
#include <hip/hip_bf16.h>

typedef float f32x4 __attribute__((ext_vector_type(4)));
typedef __bf16 bf16x8 __attribute__((ext_vector_type(8)));
typedef unsigned short ushort_t;
typedef ushort_t u16x8 __attribute__((ext_vector_type(8)));

#define GLDS16(gp, lp)                                                        \
  __builtin_amdgcn_global_load_lds(                                           \
      (__attribute__((address_space(1))) void*)(gp),                          \
      (__attribute__((address_space(3))) void*)(lp), 16, 0, 0)

__device__ __forceinline__ ushort_t f2bf(float f) {
  unsigned u = __float_as_uint(f);
  unsigned r = u + 0x7fffu + ((u >> 16) & 1u);  // round-to-nearest-even
  return (ushort_t)(r >> 16);
}

__device__ __forceinline__ int swz(int row) {
  return (row & 3) ^ ((row >> 2) & 3);
}

// ---------------------------------------------------------------------------
// W1 [K=1024][N=1024] fp32 -> w1t [N][K] bf16 (transpose + convert)
// ---------------------------------------------------------------------------
__global__ __launch_bounds__(256) void prep_w1(const float* __restrict__ w1,
                                               ushort_t* __restrict__ w1t) {
  __shared__ ushort_t tile[64][80];
  const int k0 = blockIdx.x * 64;
  const int n0 = blockIdx.y * 64;
  const int tid = threadIdx.x;
#pragma unroll
  for (int it = 0; it < 16; ++it) {
    int idx = it * 256 + tid;
    int k = idx >> 6, n = idx & 63;
    tile[n][k] = f2bf(w1[(size_t)(k0 + k) * 1024 + n0 + n]);
  }
  __syncthreads();
#pragma unroll
  for (int it = 0; it < 2; ++it) {
    int idx = it * 256 + tid;
    int n = idx >> 3, kk = (idx & 7) * 8;
    bf16x8 v = *(const bf16x8*)&tile[n][kk];
    *(bf16x8*)&w1t[(size_t)(n0 + n) * 1024 + k0 + kk] = v;
  }
}

// ---------------------------------------------------------------------------
// x fp32 [64M] -> xbf bf16 row-major [65536][1024]
// ---------------------------------------------------------------------------
__global__ __launch_bounds__(256) void prep_x(const float* __restrict__ x,
                                              ushort_t* __restrict__ xbf) {
  size_t i = ((size_t)blockIdx.x * 256 + threadIdx.x) * 8;
  float4 a = *(const float4*)(x + i);
  float4 b = *(const float4*)(x + i + 4);
  u16x8 o;
  o[0] = f2bf(a.x); o[1] = f2bf(a.y); o[2] = f2bf(a.z); o[3] = f2bf(a.w);
  o[4] = f2bf(b.x); o[5] = f2bf(b.y); o[6] = f2bf(b.z); o[7] = f2bf(b.w);
  *(u16x8*)(xbf + i) = o;
}

// ---------------------------------------------------------------------------
// Fused: 128-row strip GEMM (BN=256 per n-iter, 4 iters) -> logits in LDS ->
// softmax over each 2x2 window -> weighted sum of fp32 x rows -> out.
// Block = (b*32 + i): rows b*4096 + i*128 .. +128; all 4 members of each of
// the 32 windows (j=0..31) are inside this strip.
// ---------------------------------------------------------------------------
#define FOLD_EPILOGUE(ACC, NH)                                                \
  {                                                                           \
    float bv[4], wv[4];                                                       \
    _Pragma("unroll") for (int ni = 0; ni < 4; ++ni) {                        \
      int col = nt * 256 + (NH)*128 + wn + ni * 16 + lc;                      \
      bv[ni] = b1[col];                                                       \
      wv[ni] = w2[col];                                                       \
    }                                                                         \
    _Pragma("unroll") for (int mi = 0; mi < 4; ++mi)                          \
        _Pragma("unroll") for (int r = 0; r < 4; ++r) {                       \
      float s = 0.f;                                                          \
      _Pragma("unroll") for (int ni = 0; ni < 4; ++ni) {                      \
        float h = ACC[mi][ni][r] + bv[ni];                                    \
        h = h > 0.f ? h : 0.f;                                                \
        s += h * wv[ni];                                                      \
      }                                                                       \
      racc[mi][r] += s;                                                       \
    }                                                                         \
  }

template <bool A_BF16>
__global__ __launch_bounds__(256, 2) void gemm_fused(
    const void* __restrict__ aglob, const ushort_t* __restrict__ w1t,
    const float* __restrict__ b1, const float* __restrict__ w2,
    const float* __restrict__ x, float* __restrict__ out) {
  __shared__ ushort_t As[128 * 32];   // 8 KB
  __shared__ ushort_t Bs0[128 * 32];  // 8 KB
  __shared__ ushort_t Bs1[128 * 32];  // 8 KB
  __shared__ float lbuf[128];
  __shared__ float abuf[128];  // alpha[j*4+k]

  const int tid = threadIdx.x;
  const int wave = tid >> 6, lane = tid & 63;
  const int quad = lane >> 4, lc = lane & 15;
  const int m0 = blockIdx.x * 128;
  const int wm = (wave & 1) * 64, wn = (wave >> 1) * 64;

  // Staging: thread covers LDS chunks g0/g1 (16 B each); source chunk swizzled
  const int g0 = tid, g1 = 256 + tid;
  const int r0 = g0 >> 2, c0 = (g0 & 3) ^ swz(g0 >> 2);
  const int r1 = g1 >> 2, c1 = (g1 & 3) ^ swz(g1 >> 2);
  ushort_t* adst0 = As + g0 * 8;
  ushort_t* adst1 = As + g1 * 8;
  const ushort_t* abf0 = nullptr; const ushort_t* abf1 = nullptr;
  const float* af0 = nullptr; const float* af1 = nullptr;
  if constexpr (A_BF16) {
    abf0 = (const ushort_t*)aglob + (size_t)(m0 + r0) * 1024 + c0 * 8;
    abf1 = (const ushort_t*)aglob + (size_t)(m0 + r1) * 1024 + c1 * 8;
  } else {
    af0 = (const float*)aglob + (size_t)(m0 + r0) * 1024 + c0 * 8;
    af1 = (const float*)aglob + (size_t)(m0 + r1) * 1024 + c1 * 8;
  }
  const ushort_t* b00 = w1t + (size_t)r0 * 1024 + c0 * 8;         // Bs0 tile
  const ushort_t* b01 = w1t + (size_t)r1 * 1024 + c1 * 8;
  const ushort_t* b10 = w1t + (size_t)(128 + r0) * 1024 + c0 * 8; // Bs1 tile
  const ushort_t* b11 = w1t + (size_t)(128 + r1) * 1024 + c1 * 8;

  int aoff[4], boff[4];
#pragma unroll
  for (int mi = 0; mi < 4; ++mi) {
    int r = wm + mi * 16 + lc;
    aoff[mi] = r * 32 + (quad ^ swz(r)) * 8;
  }
#pragma unroll
  for (int ni = 0; ni < 4; ++ni) {
    int r = wn + ni * 16 + lc;
    boff[ni] = r * 32 + (quad ^ swz(r)) * 8;
  }

  float racc[4][4] = {};

  for (int nt = 0; nt < 4; ++nt) {
    const size_t cb = (size_t)nt * 256 * 1024;
    f32x4 acc0[4][4] = {};
    f32x4 acc1[4][4] = {};
    for (int kt = 0; kt < 32; ++kt) {
      const int k0 = kt * 32;
      __syncthreads();
      GLDS16(b00 + cb + k0, Bs0 + g0 * 8);
      GLDS16(b01 + cb + k0, Bs0 + g1 * 8);
      GLDS16(b10 + cb + k0, Bs1 + g0 * 8);
      GLDS16(b11 + cb + k0, Bs1 + g1 * 8);
      if constexpr (A_BF16) {
        GLDS16(abf0 + k0, adst0);
        GLDS16(abf1 + k0, adst1);
      } else {
        float4 v0 = *(const float4*)(af0 + k0);
        float4 v1 = *(const float4*)(af0 + k0 + 4);
        float4 v2 = *(const float4*)(af1 + k0);
        float4 v3 = *(const float4*)(af1 + k0 + 4);
        u16x8 o0, o1;
        o0[0] = f2bf(v0.x); o0[1] = f2bf(v0.y); o0[2] = f2bf(v0.z); o0[3] = f2bf(v0.w);
        o0[4] = f2bf(v1.x); o0[5] = f2bf(v1.y); o0[6] = f2bf(v1.z); o0[7] = f2bf(v1.w);
        o1[0] = f2bf(v2.x); o1[1] = f2bf(v2.y); o1[2] = f2bf(v2.z); o1[3] = f2bf(v2.w);
        o1[4] = f2bf(v3.x); o1[5] = f2bf(v3.y); o1[6] = f2bf(v3.z); o1[7] = f2bf(v3.w);
        *(u16x8*)adst0 = o0;
        *(u16x8*)adst1 = o1;
      }
      __syncthreads();

      bf16x8 afr[4], bfr0[4], bfr1[4];
#pragma unroll
      for (int mi = 0; mi < 4; ++mi) afr[mi] = *(const bf16x8*)&As[aoff[mi]];
#pragma unroll
      for (int ni = 0; ni < 4; ++ni) {
        bfr0[ni] = *(const bf16x8*)&Bs0[boff[ni]];
        bfr1[ni] = *(const bf16x8*)&Bs1[boff[ni]];
      }
#pragma unroll
      for (int mi = 0; mi < 4; ++mi)
#pragma unroll
        for (int ni = 0; ni < 4; ++ni) {
          acc0[mi][ni] = __builtin_amdgcn_mfma_f32_16x16x32_bf16(
              afr[mi], bfr0[ni], acc0[mi][ni], 0, 0, 0);
          acc1[mi][ni] = __builtin_amdgcn_mfma_f32_16x16x32_bf16(
              afr[mi], bfr1[ni], acc1[mi][ni], 0, 0, 0);
        }
    }
    FOLD_EPILOGUE(acc0, 0)
    FOLD_EPILOGUE(acc1, 1)
  }

  // Reduce racc over the 16 columns per lane-group -> per-row logits in LDS.
#pragma unroll
  for (int mi = 0; mi < 4; ++mi)
#pragma unroll
    for (int r = 0; r < 4; ++r)
#pragma unroll
      for (int off = 1; off < 16; off <<= 1)
        racc[mi][r] += __shfl_xor(racc[mi][r], off, 64);
  __syncthreads();
  if (tid < 128) lbuf[tid] = 0.f;
  __syncthreads();
  if (lc == 0) {
#pragma unroll
    for (int mi = 0; mi < 4; ++mi)
#pragma unroll
      for (int r = 0; r < 4; ++r)
        atomicAdd(&lbuf[wm + mi * 16 + quad * 4 + r], racc[mi][r]);
  }
  __syncthreads();

  // Softmax per 2x2 window (b2 omitted: shift-invariant).
  if (tid < 32) {
    const int j = tid;
    float l0 = lbuf[2 * j], l1 = lbuf[2 * j + 1];
    float l2 = lbuf[64 + 2 * j], l3 = lbuf[65 + 2 * j];
    float mx = fmaxf(fmaxf(l0, l1), fmaxf(l2, l3));
    float e0 = __expf(l0 - mx), e1 = __expf(l1 - mx);
    float e2 = __expf(l2 - mx), e3 = __expf(l3 - mx);
    float inv = 1.0f / (e0 + e1 + e2 + e3);
    abuf[j * 4 + 0] = e0 * inv;
    abuf[j * 4 + 1] = e1 * inv;
    abuf[j * 4 + 2] = e2 * inv;
    abuf[j * 4 + 3] = e3 * inv;
  }
  __syncthreads();

  // Weighted sum: out row b*1024 + i*32 + j  (block = b*32 + i).
  const int b = blockIdx.x >> 5, ii = blockIdx.x & 31;
  const float* xs = x + (size_t)m0 * 1024;
  float* orow = out + ((size_t)(b * 1024 + ii * 32)) * 1024;
  for (int j = 0; j < 32; ++j) {
    float a0 = abuf[j * 4 + 0], a1 = abuf[j * 4 + 1];
    float a2 = abuf[j * 4 + 2], a3 = abuf[j * 4 + 3];
    const float4* p0 = (const float4*)(xs + (size_t)(2 * j) * 1024);
    const float4* p1 = (const float4*)(xs + (size_t)(2 * j + 1) * 1024);
    const float4* p2 = (const float4*)(xs + (size_t)(64 + 2 * j) * 1024);
    const float4* p3 = (const float4*)(xs + (size_t)(65 + 2 * j) * 1024);
    float4 v0 = p0[tid], v1 = p1[tid], v2 = p2[tid], v3 = p3[tid];
    float4 o;
    o.x = a0 * v0.x + a1 * v1.x + a2 * v2.x + a3 * v3.x;
    o.y = a0 * v0.y + a1 * v1.y + a2 * v2.y + a3 * v3.y;
    o.z = a0 * v0.z + a1 * v1.z + a2 * v2.z + a3 * v3.z;
    o.w = a0 * v0.w + a1 * v1.w + a2 * v2.w + a3 * v3.w;
    ((float4*)(orow + (size_t)j * 1024))[tid] = o;
  }
}

// ---------------------------------------------------------------------------
extern "C" void kernel_launch(void* const* d_in, const int* in_sizes, int n_in,
                              void* d_out, int out_size, void* d_ws,
                              size_t ws_size, hipStream_t stream) {
  const float* x  = (const float*)d_in[0];  // [16, 4096, 1024]
  const float* W1 = (const float*)d_in[1];  // [1024, 1024]
  const float* b1 = (const float*)d_in[2];  // [1024]
  const float* W2 = (const float*)d_in[3];  // [1024, 1]
  float* out = (float*)d_out;               // [16, 1024, 1024]

  const size_t XBF_BYTES = 134217728ull;  // 64M bf16
  const size_t W1T_BYTES = 2097152ull;

  if (ws_size >= XBF_BYTES + W1T_BYTES) {
    ushort_t* xbf = (ushort_t*)d_ws;
    ushort_t* w1t = (ushort_t*)((char*)d_ws + XBF_BYTES);
    prep_x<<<32768, 256, 0, stream>>>(x, xbf);
    prep_w1<<<dim3(16, 16), 256, 0, stream>>>(W1, w1t);
    gemm_fused<true><<<512, 256, 0, stream>>>(xbf, w1t, b1, W2, x, out);
  } else {
    ushort_t* w1t = (ushort_t*)d_ws;
    prep_w1<<<dim3(16, 16), 256, 0, stream>>>(W1, w1t);
    gemm_fused<false><<<512, 256, 0, stream>>>(x, w1t, b1, W2, x, out);
  }
}